// Round 1
// baseline (370.544 us; speedup 1.0000x reference)
//
#include <hip/hip_runtime.h>
#include <math.h>

// VQ-VAE vector quantizer for MI355X (gfx950).
// z: [32768, 64] fp32, codebook: [1024, 64] fp32.
// Outputs (flat float32, concatenated): quantized_st [32768*64], vq_loss [1],
// indices [32768] (as float), perplexity [1].

#define D 64
#define ROWS_PER_BLOCK 64
#define CHUNK 256  // codes per wave (K / 4 waves)

__global__ __launch_bounds__(256) void vq_norms(const float* __restrict__ cb,
                                                float* __restrict__ norms, int K) {
  int k = blockIdx.x * blockDim.x + threadIdx.x;
  if (k < K) {
    const float4* e = (const float4*)(cb + (size_t)k * D);
    float s0 = 0.f, s1 = 0.f, s2 = 0.f, s3 = 0.f;
#pragma unroll
    for (int i = 0; i < D / 4; ++i) {
      float4 v = e[i];
      s0 = fmaf(v.x, v.x, s0);
      s1 = fmaf(v.y, v.y, s1);
      s2 = fmaf(v.z, v.z, s2);
      s3 = fmaf(v.w, v.w, s3);
    }
    norms[k] = (s0 + s1) + (s2 + s3);
  }
}

__global__ __launch_bounds__(256) void vq_main(
    const float* __restrict__ z, const float* __restrict__ cb,
    const float* __restrict__ cbn, float* __restrict__ out_q,
    float* __restrict__ out_idx, unsigned int* __restrict__ hist,
    float* __restrict__ loss_acc) {
  __shared__ float sd[4][ROWS_PER_BLOCK];
  __shared__ int sk[4][ROWS_PER_BLOCK];
  __shared__ float swav[4];

  const int lane = threadIdx.x & 63;  // row within block
  const int wav = threadIdx.x >> 6;   // K-chunk 0..3
  const int row = blockIdx.x * ROWS_PER_BLOCK + lane;

  // z row into registers (64 VGPRs). All 4 waves of the block load the same
  // 64 rows -> L1 serves waves 1-3.
  float zr[D];
  const float4* zp = (const float4*)(z + (size_t)row * D);
#pragma unroll
  for (int i = 0; i < D / 4; ++i) {
    float4 v = zp[i];
    zr[4 * i + 0] = v.x;
    zr[4 * i + 1] = v.y;
    zr[4 * i + 2] = v.z;
    zr[4 * i + 3] = v.w;
  }

  // rz = ||z||^2 (4-way split accumulators)
  float r0 = 0.f, r1 = 0.f, r2 = 0.f, r3 = 0.f;
#pragma unroll
  for (int i = 0; i < D; i += 4) {
    r0 = fmaf(zr[i + 0], zr[i + 0], r0);
    r1 = fmaf(zr[i + 1], zr[i + 1], r1);
    r2 = fmaf(zr[i + 2], zr[i + 2], r2);
    r3 = fmaf(zr[i + 3], zr[i + 3], r3);
  }
  const float rz = (r0 + r1) + (r2 + r3);

  // Each wave scans a contiguous 256-code chunk; k is wave-uniform so the
  // codebook loads broadcast within the wave.
  float best_d = 3.4e38f;
  int best_k = 0;
  const int k0 = wav * CHUNK;
  for (int kk = 0; kk < CHUNK; ++kk) {
    const int k = k0 + kk;
    const float4* e4 = (const float4*)(cb + (size_t)k * D);
    float d0 = 0.f, d1 = 0.f, d2 = 0.f, d3 = 0.f;
#pragma unroll
    for (int i = 0; i < D / 4; ++i) {
      float4 v = e4[i];
      d0 = fmaf(zr[4 * i + 0], v.x, d0);
      d1 = fmaf(zr[4 * i + 1], v.y, d1);
      d2 = fmaf(zr[4 * i + 2], v.z, d2);
      d3 = fmaf(zr[4 * i + 3], v.w, d3);
    }
    float dot = (d0 + d1) + (d2 + d3);
    // same formula shape as reference: (||z||^2 + ||e||^2) - 2*dot
    float dist = (rz + cbn[k]) - 2.0f * dot;
    if (dist < best_d) {  // strict < keeps first (lowest) index, like np.argmin
      best_d = dist;
      best_k = k;
    }
  }

  sd[wav][lane] = best_d;
  sk[wav][lane] = best_k;
  __syncthreads();

  if (wav == 0) {
    // chunks are ascending in k; strict < keeps the lowest-k tie
#pragma unroll
    for (int j = 1; j < 4; ++j) {
      float dj = sd[j][lane];
      int kj = sk[j][lane];
      if (dj < best_d) {
        best_d = dj;
        best_k = kj;
      }
    }
    sk[0][lane] = best_k;
    out_idx[row] = (float)best_k;
    atomicAdd(&hist[best_k], 1u);
  }
  __syncthreads();

  // Cooperative, coalesced quantized write + loss partial.
  // 64 rows * 16 float4 = 1024 float4 per block; 256 threads x 4 iters.
  float lsum = 0.f;
#pragma unroll
  for (int it = 0; it < 4; ++it) {
    int f4 = it * 256 + threadIdx.x;
    int r = f4 >> 4;
    int c4 = (f4 & 15) * 4;
    int bk = sk[0][r];
    const float4 q = *(const float4*)(cb + (size_t)bk * D + c4);
    const int grow = blockIdx.x * ROWS_PER_BLOCK + r;
    const float4 zv = *(const float4*)(z + (size_t)grow * D + c4);
    *(float4*)(out_q + (size_t)grow * D + c4) = q;
    float ax = q.x - zv.x, ay = q.y - zv.y, az = q.z - zv.z, aw = q.w - zv.w;
    lsum += ax * ax + ay * ay + az * az + aw * aw;
  }
  // wave64 tree reduce, then one atomic per block
#pragma unroll
  for (int off = 32; off > 0; off >>= 1) lsum += __shfl_down(lsum, off, 64);
  if (lane == 0) swav[wav] = lsum;
  __syncthreads();
  if (threadIdx.x == 0) {
    atomicAdd(loss_acc, (swav[0] + swav[1]) + (swav[2] + swav[3]));
  }
}

__global__ __launch_bounds__(1024) void vq_final(
    const unsigned int* __restrict__ hist, const float* __restrict__ loss_acc,
    float* __restrict__ out_loss, float* __restrict__ out_perp, float inv_n,
    float inv_nd) {
  __shared__ float red[1024];
  int t = threadIdx.x;
  float p = (float)hist[t] * inv_n;
  red[t] = p * logf(p + 1e-10f);
  __syncthreads();
  for (int s = 512; s > 0; s >>= 1) {
    if (t < s) red[t] += red[t + s];
    __syncthreads();
  }
  if (t == 0) {
    *out_perp = expf(-red[0]);
    // q_latent + 0.25*e_latent, both numerically mean((q-z)^2)
    *out_loss = 1.25f * loss_acc[0] * inv_nd;
  }
}

extern "C" void kernel_launch(void* const* d_in, const int* in_sizes, int n_in,
                              void* d_out, int out_size, void* d_ws,
                              size_t ws_size, hipStream_t stream) {
  (void)n_in;
  (void)out_size;
  (void)ws_size;
  const float* z = (const float*)d_in[0];
  const float* cb = (const float*)d_in[1];
  const int N = in_sizes[0] / D;  // 32768
  const int K = in_sizes[1] / D;  // 1024

  // Output layout (flat float32, reference return order):
  float* out_q = (float*)d_out;                      // N*D
  float* out_loss = (float*)d_out + (size_t)N * D;   // 1
  float* out_idx = out_loss + 1;                     // N
  float* out_perp = out_idx + N;                     // 1

  // Workspace: hist[K] (uint), loss_acc[1] (float), pad, cbn[K] (float)
  unsigned int* hist = (unsigned int*)d_ws;
  float* loss_acc = (float*)d_ws + K;
  float* cbn = (float*)d_ws + K + 8;  // 16B-aligned

  // ws is re-poisoned to 0xAA before every timed launch -> zero accumulators.
  hipMemsetAsync(d_ws, 0, (size_t)(K + 1) * sizeof(float), stream);

  vq_norms<<<dim3((K + 255) / 256), dim3(256), 0, stream>>>(cb, cbn, K);
  vq_main<<<dim3(N / ROWS_PER_BLOCK), dim3(256), 0, stream>>>(
      z, cb, cbn, out_q, out_idx, hist, loss_acc);
  vq_final<<<dim3(1), dim3(1024), 0, stream>>>(
      hist, loss_acc, out_loss, out_perp, 1.0f / (float)N,
      1.0f / ((float)N * (float)D));
}

// Round 2
// 154.158 us; speedup vs baseline: 2.4037x; 2.4037x over previous
//
#include <hip/hip_runtime.h>
#include <math.h>

// VQ-VAE vector quantizer for MI355X (gfx950).
// z: [32768, 64] fp32, codebook: [1024, 64] fp32.
// Outputs (flat float32, concatenated): quantized_st [32768*64], vq_loss [1],
// indices [32768] (as float), perplexity [1].
//
// R2: fp32 VALU floor is ~27 us (2.1e9 FMA / 78.6 T FMA/s). R1 ran at 317 us
// because the compiler's occupancy heuristic capped VGPRs at 48 (no
// launch_bounds min-waves arg), evicting the 64-float z row from registers ->
// latency-bound inner loop (VALUBusy 12%). Fix: __launch_bounds__(256,2)
// (VGPR cap 256) + wave-private LDS staging of the codebook chunk with
// register prefetch, so the inner loop is ds_read_b128 (broadcast) + v_fmac.

#define D 64
#define ROWS_PER_BLOCK 64
#define CHUNK 256  // codes per wave (K / 4 waves)
#define SUB 64     // codes per staged subtile (16 KB per wave)

__global__ __launch_bounds__(256) void vq_norms(const float* __restrict__ cb,
                                                float* __restrict__ norms, int K) {
  int k = blockIdx.x * blockDim.x + threadIdx.x;
  if (k < K) {
    const float4* e = (const float4*)(cb + (size_t)k * D);
    float s0 = 0.f, s1 = 0.f, s2 = 0.f, s3 = 0.f;
#pragma unroll
    for (int i = 0; i < D / 4; ++i) {
      float4 v = e[i];
      s0 = fmaf(v.x, v.x, s0);
      s1 = fmaf(v.y, v.y, s1);
      s2 = fmaf(v.z, v.z, s2);
      s3 = fmaf(v.w, v.w, s3);
    }
    norms[k] = (s0 + s1) + (s2 + s3);
  }
}

__global__ __launch_bounds__(256, 2) void vq_main(
    const float* __restrict__ z, const float* __restrict__ cb,
    const float* __restrict__ cbn, float* __restrict__ out_q,
    float* __restrict__ out_idx, unsigned int* __restrict__ hist,
    float* __restrict__ loss_acc) {
  // 4 waves x 64 codes x 64 floats = 64 KB -> 2 blocks/CU (128 KB of 160 KB)
  __shared__ float lcode[4 * SUB * D];
  __shared__ float sd[4][ROWS_PER_BLOCK];
  __shared__ int sk[4][ROWS_PER_BLOCK];
  __shared__ float swav[4];

  const int lane = threadIdx.x & 63;  // row within block
  const int wav = threadIdx.x >> 6;   // K-chunk 0..3
  const int row = blockIdx.x * ROWS_PER_BLOCK + lane;

  // z row into registers (64 VGPRs; launch_bounds(256,2) keeps it resident).
  float zr[D];
  const float4* zp = (const float4*)(z + (size_t)row * D);
#pragma unroll
  for (int i = 0; i < D / 4; ++i) {
    float4 v = zp[i];
    zr[4 * i + 0] = v.x;
    zr[4 * i + 1] = v.y;
    zr[4 * i + 2] = v.z;
    zr[4 * i + 3] = v.w;
  }

  // rz = ||z||^2 (4-way split accumulators)
  float r0 = 0.f, r1 = 0.f, r2 = 0.f, r3 = 0.f;
#pragma unroll
  for (int i = 0; i < D; i += 4) {
    r0 = fmaf(zr[i + 0], zr[i + 0], r0);
    r1 = fmaf(zr[i + 1], zr[i + 1], r1);
    r2 = fmaf(zr[i + 2], zr[i + 2], r2);
    r3 = fmaf(zr[i + 3], zr[i + 3], r3);
  }
  const float rz = (r0 + r1) + (r2 + r3);

  // Each wave scans a contiguous 256-code chunk in 4 subtiles of 64 codes,
  // staged through a wave-private LDS region (no __syncthreads needed) with
  // register prefetch of the next subtile (hides global latency).
  float best_d = 3.4e38f;
  int best_k = 0;
  const int k0 = wav * CHUNK;

  const float4* cb4 = (const float4*)cb;
  float4* lc4 = (float4*)(lcode + wav * (SUB * D));
  const float* ebase = lcode + wav * (SUB * D);

  float4 pre[16];
  {
    const float4* src = cb4 + (size_t)k0 * (D / 4);
#pragma unroll
    for (int j = 0; j < 16; ++j) pre[j] = src[j * 64 + lane];
  }

#pragma unroll
  for (int s = 0; s < CHUNK / SUB; ++s) {
    // commit prefetched subtile to LDS (coalesced float4, same linear order)
#pragma unroll
    for (int j = 0; j < 16; ++j) lc4[j * 64 + lane] = pre[j];
    // prefetch next subtile into registers
    if (s + 1 < CHUNK / SUB) {
      const float4* src = cb4 + (size_t)(k0 + (s + 1) * SUB) * (D / 4);
#pragma unroll
      for (int j = 0; j < 16; ++j) pre[j] = src[j * 64 + lane];
    }
    // compute: all lanes read the same code -> LDS broadcast, conflict-free
    const int kb = k0 + s * SUB;
    for (int kk = 0; kk < SUB; ++kk) {
      const float4* e4 = (const float4*)(ebase + kk * D);
      float d0 = 0.f, d1 = 0.f, d2 = 0.f, d3 = 0.f;
#pragma unroll
      for (int i = 0; i < D / 4; ++i) {
        float4 v = e4[i];
        d0 = fmaf(zr[4 * i + 0], v.x, d0);
        d1 = fmaf(zr[4 * i + 1], v.y, d1);
        d2 = fmaf(zr[4 * i + 2], v.z, d2);
        d3 = fmaf(zr[4 * i + 3], v.w, d3);
      }
      float dot = (d0 + d1) + (d2 + d3);
      const int k = kb + kk;
      // same formula shape as reference: (||z||^2 + ||e||^2) - 2*dot
      float dist = (rz + cbn[k]) - 2.0f * dot;
      if (dist < best_d) {  // strict < keeps first (lowest) index, like np.argmin
        best_d = dist;
        best_k = k;
      }
    }
  }

  sd[wav][lane] = best_d;
  sk[wav][lane] = best_k;
  __syncthreads();

  if (wav == 0) {
    // chunks are ascending in k; strict < keeps the lowest-k tie
#pragma unroll
    for (int j = 1; j < 4; ++j) {
      float dj = sd[j][lane];
      int kj = sk[j][lane];
      if (dj < best_d) {
        best_d = dj;
        best_k = kj;
      }
    }
    sk[0][lane] = best_k;
    out_idx[row] = (float)best_k;
    atomicAdd(&hist[best_k], 1u);
  }
  __syncthreads();

  // Cooperative, coalesced quantized write + loss partial.
  // 64 rows * 16 float4 = 1024 float4 per block; 256 threads x 4 iters.
  float lsum = 0.f;
#pragma unroll
  for (int it = 0; it < 4; ++it) {
    int f4 = it * 256 + threadIdx.x;
    int r = f4 >> 4;
    int c4 = (f4 & 15) * 4;
    int bk = sk[0][r];
    const float4 q = *(const float4*)(cb + (size_t)bk * D + c4);
    const int grow = blockIdx.x * ROWS_PER_BLOCK + r;
    const float4 zv = *(const float4*)(z + (size_t)grow * D + c4);
    *(float4*)(out_q + (size_t)grow * D + c4) = q;
    float ax = q.x - zv.x, ay = q.y - zv.y, az = q.z - zv.z, aw = q.w - zv.w;
    lsum += ax * ax + ay * ay + az * az + aw * aw;
  }
  // wave64 tree reduce, then one atomic per block
#pragma unroll
  for (int off = 32; off > 0; off >>= 1) lsum += __shfl_down(lsum, off, 64);
  if (lane == 0) swav[wav] = lsum;
  __syncthreads();
  if (threadIdx.x == 0) {
    atomicAdd(loss_acc, (swav[0] + swav[1]) + (swav[2] + swav[3]));
  }
}

__global__ __launch_bounds__(1024) void vq_final(
    const unsigned int* __restrict__ hist, const float* __restrict__ loss_acc,
    float* __restrict__ out_loss, float* __restrict__ out_perp, float inv_n,
    float inv_nd) {
  __shared__ float red[1024];
  int t = threadIdx.x;
  float p = (float)hist[t] * inv_n;
  red[t] = p * logf(p + 1e-10f);
  __syncthreads();
  for (int s = 512; s > 0; s >>= 1) {
    if (t < s) red[t] += red[t + s];
    __syncthreads();
  }
  if (t == 0) {
    *out_perp = expf(-red[0]);
    // q_latent + 0.25*e_latent, both numerically mean((q-z)^2)
    *out_loss = 1.25f * loss_acc[0] * inv_nd;
  }
}

extern "C" void kernel_launch(void* const* d_in, const int* in_sizes, int n_in,
                              void* d_out, int out_size, void* d_ws,
                              size_t ws_size, hipStream_t stream) {
  (void)n_in;
  (void)out_size;
  (void)ws_size;
  const float* z = (const float*)d_in[0];
  const float* cb = (const float*)d_in[1];
  const int N = in_sizes[0] / D;  // 32768
  const int K = in_sizes[1] / D;  // 1024

  // Output layout (flat float32, reference return order):
  float* out_q = (float*)d_out;                      // N*D
  float* out_loss = (float*)d_out + (size_t)N * D;   // 1
  float* out_idx = out_loss + 1;                     // N
  float* out_perp = out_idx + N;                     // 1

  // Workspace: hist[K] (uint), loss_acc[1] (float), pad, cbn[K] (float)
  unsigned int* hist = (unsigned int*)d_ws;
  float* loss_acc = (float*)d_ws + K;
  float* cbn = (float*)d_ws + K + 8;  // 16B-aligned

  // ws is poisoned 0xAA before every launch -> must zero accumulators.
  hipMemsetAsync(d_ws, 0, (size_t)(K + 1) * sizeof(float), stream);

  vq_norms<<<dim3((K + 255) / 256), dim3(256), 0, stream>>>(cb, cbn, K);
  vq_main<<<dim3(N / ROWS_PER_BLOCK), dim3(256), 0, stream>>>(
      z, cb, cbn, out_q, out_idx, hist, loss_acc);
  vq_final<<<dim3(1), dim3(1024), 0, stream>>>(
      hist, loss_acc, out_loss, out_perp, 1.0f / (float)N,
      1.0f / ((float)N * (float)D));
}

// Round 3
// 136.491 us; speedup vs baseline: 2.7148x; 1.1294x over previous
//
#include <hip/hip_runtime.h>
#include <math.h>

// VQ-VAE vector quantizer for MI355X (gfx950).
// z: [32768, 64] fp32, codebook: [1024, 64] fp32.
// Outputs (flat float32, concatenated): quantized_st [32768*64], vq_loss [1],
// indices [32768] (as float), perplexity [1].
//
// R3: R2 was LDS-pipe-bound: 16 broadcast ds_read_b128 per code-step (~6 cyc
// each on the CU's one LDS pipe) vs 288 VALU cyc/SIMD -> VALUBusy 39%,
// 103 us ~= 8.4e6 b128 * 6 cyc / (256 CU * 2.4 GHz). Fix: 2 rows per lane
// (zr[2][64] = 128 VGPRs) halves ds_read per (row,code) pair. 512-thread
// blocks, 8 waves x 128-code chunks, 128 rows/block.

#define D 64
#define RPL 2                 // rows per lane
#define WAVES 8
#define ROWS (64 * RPL)       // 128 rows per block
#define KCODES 1024
#define WCHUNK (KCODES / WAVES)  // 128 codes per wave
#define SUB 32                // codes per staged subtile (8 KB per wave)

__global__ __launch_bounds__(256) void vq_norms(const float* __restrict__ cb,
                                                float* __restrict__ norms,
                                                unsigned int* __restrict__ hist,
                                                float* __restrict__ loss_acc,
                                                int K) {
  int k = blockIdx.x * blockDim.x + threadIdx.x;
  if (k < K) {
    const float4* e = (const float4*)(cb + (size_t)k * D);
    float s0 = 0.f, s1 = 0.f, s2 = 0.f, s3 = 0.f;
#pragma unroll
    for (int i = 0; i < D / 4; ++i) {
      float4 v = e[i];
      s0 = fmaf(v.x, v.x, s0);
      s1 = fmaf(v.y, v.y, s1);
      s2 = fmaf(v.z, v.z, s2);
      s3 = fmaf(v.w, v.w, s3);
    }
    norms[k] = (s0 + s1) + (s2 + s3);
    hist[k] = 0u;  // ws is poisoned 0xAA before every launch
  }
  if (k == 0) loss_acc[0] = 0.f;
}

__global__ __launch_bounds__(512, 2) void vq_main(
    const float* __restrict__ z, const float* __restrict__ cb,
    const float* __restrict__ cbn, float* __restrict__ out_q,
    float* __restrict__ out_idx, unsigned int* __restrict__ hist,
    float* __restrict__ loss_acc) {
  // 8 waves x 32 codes x 64 floats = 64 KB staging (wave-private, no barrier)
  __shared__ float lcode[WAVES * SUB * D];
  __shared__ float sd[WAVES][ROWS];
  __shared__ int sk[WAVES][ROWS];
  __shared__ float swav[WAVES];

  const int tid = threadIdx.x;
  const int lane = tid & 63;
  const int wav = __builtin_amdgcn_readfirstlane(tid >> 6);  // uniform
  const int rowbase = blockIdx.x * ROWS;

  // 2 z-rows per lane in registers (128 VGPRs; launch_bounds(512,2) -> cap 256)
  float zr[RPL][D];
  float rz[RPL];
#pragma unroll
  for (int r = 0; r < RPL; ++r) {
    const float4* zp = (const float4*)(z + (size_t)(rowbase + 64 * r + lane) * D);
    float s0 = 0.f, s1 = 0.f, s2 = 0.f, s3 = 0.f;
#pragma unroll
    for (int i = 0; i < D / 4; ++i) {
      float4 v = zp[i];
      zr[r][4 * i + 0] = v.x;
      zr[r][4 * i + 1] = v.y;
      zr[r][4 * i + 2] = v.z;
      zr[r][4 * i + 3] = v.w;
      s0 = fmaf(v.x, v.x, s0);
      s1 = fmaf(v.y, v.y, s1);
      s2 = fmaf(v.z, v.z, s2);
      s3 = fmaf(v.w, v.w, s3);
    }
    rz[r] = (s0 + s1) + (s2 + s3);
  }

  float best_d[RPL];
  int best_k[RPL];
#pragma unroll
  for (int r = 0; r < RPL; ++r) {
    best_d[r] = 3.4e38f;
    best_k[r] = 0;
  }

  const int k0 = wav * WCHUNK;
  const float4* cb4 = (const float4*)cb;
  float4* lc4 = (float4*)(lcode + wav * (SUB * D));
  const float* ebase = lcode + wav * (SUB * D);

  // register prefetch of the first subtile (8 float4/lane = one 8 KB subtile)
  float4 pre[8];
  {
    const float4* src = cb4 + (size_t)k0 * (D / 4);
#pragma unroll
    for (int j = 0; j < 8; ++j) pre[j] = src[j * 64 + lane];
  }

#pragma unroll
  for (int s = 0; s < WCHUNK / SUB; ++s) {
    // commit prefetched subtile to wave-private LDS (linear float4 order)
#pragma unroll
    for (int j = 0; j < 8; ++j) lc4[j * 64 + lane] = pre[j];
    if (s + 1 < WCHUNK / SUB) {
      const float4* src = cb4 + (size_t)(k0 + (s + 1) * SUB) * (D / 4);
#pragma unroll
      for (int j = 0; j < 8; ++j) pre[j] = src[j * 64 + lane];
    }
    const int kb = k0 + s * SUB;
    for (int kk = 0; kk < SUB; ++kk) {
      const float4* e4 = (const float4*)(ebase + kk * D);
      float d0[RPL], d1[RPL], d2[RPL], d3[RPL];
#pragma unroll
      for (int r = 0; r < RPL; ++r) d0[r] = d1[r] = d2[r] = d3[r] = 0.f;
#pragma unroll
      for (int i = 0; i < D / 4; ++i) {
        float4 v = e4[i];  // broadcast: all lanes same addr, conflict-free
#pragma unroll
        for (int r = 0; r < RPL; ++r) {
          d0[r] = fmaf(zr[r][4 * i + 0], v.x, d0[r]);
          d1[r] = fmaf(zr[r][4 * i + 1], v.y, d1[r]);
          d2[r] = fmaf(zr[r][4 * i + 2], v.z, d2[r]);
          d3[r] = fmaf(zr[r][4 * i + 3], v.w, d3[r]);
        }
      }
      const int k = kb + kk;
      const float en = cbn[k];  // wave-uniform index -> scalar load
#pragma unroll
      for (int r = 0; r < RPL; ++r) {
        float dot = (d0[r] + d1[r]) + (d2[r] + d3[r]);
        // same formula shape as reference: (||z||^2 + ||e||^2) - 2*dot
        float dist = (rz[r] + en) - 2.0f * dot;
        if (dist < best_d[r]) {  // strict <: first (lowest) index wins ties
          best_d[r] = dist;
          best_k[r] = k;
        }
      }
    }
  }

#pragma unroll
  for (int r = 0; r < RPL; ++r) {
    sd[wav][64 * r + lane] = best_d[r];
    sk[wav][64 * r + lane] = best_k[r];
  }
  __syncthreads();

  // cross-wave argmin: waves cover ascending k; strict < keeps lowest-k tie
  if (tid < ROWS) {
    float bd = sd[0][tid];
    int bk = sk[0][tid];
#pragma unroll
    for (int j = 1; j < WAVES; ++j) {
      float dj = sd[j][tid];
      if (dj < bd) {
        bd = dj;
        bk = sk[j][tid];
      }
    }
    sk[0][tid] = bk;
    out_idx[rowbase + tid] = (float)bk;
    atomicAdd(&hist[bk], 1u);
  }
  __syncthreads();

  // Cooperative quantized write + loss partial.
  // 128 rows * 16 float4 = 2048 float4; 512 threads x 4 iters.
  float lsum = 0.f;
#pragma unroll
  for (int it = 0; it < 4; ++it) {
    int f4 = it * 512 + tid;
    int r = f4 >> 4;
    int c4 = (f4 & 15) * 4;
    int bk = sk[0][r];
    const float4 q = *(const float4*)(cb + (size_t)bk * D + c4);
    const int grow = rowbase + r;
    const float4 zv = *(const float4*)(z + (size_t)grow * D + c4);
    *(float4*)(out_q + (size_t)grow * D + c4) = q;
    float ax = q.x - zv.x, ay = q.y - zv.y, az = q.z - zv.z, aw = q.w - zv.w;
    lsum += ax * ax + ay * ay + az * az + aw * aw;
  }
#pragma unroll
  for (int off = 32; off > 0; off >>= 1) lsum += __shfl_down(lsum, off, 64);
  if (lane == 0) swav[wav] = lsum;
  __syncthreads();
  if (tid == 0) {
    float t = 0.f;
#pragma unroll
    for (int j = 0; j < WAVES; ++j) t += swav[j];
    atomicAdd(loss_acc, t);
  }
}

__global__ __launch_bounds__(1024) void vq_final(
    const unsigned int* __restrict__ hist, const float* __restrict__ loss_acc,
    float* __restrict__ out_loss, float* __restrict__ out_perp, float inv_n,
    float inv_nd) {
  __shared__ float red[1024];
  int t = threadIdx.x;
  float p = (float)hist[t] * inv_n;
  red[t] = p * logf(p + 1e-10f);
  __syncthreads();
  for (int s = 512; s > 0; s >>= 1) {
    if (t < s) red[t] += red[t + s];
    __syncthreads();
  }
  if (t == 0) {
    *out_perp = expf(-red[0]);
    // q_latent + 0.25*e_latent, both numerically mean((q-z)^2)
    *out_loss = 1.25f * loss_acc[0] * inv_nd;
  }
}

extern "C" void kernel_launch(void* const* d_in, const int* in_sizes, int n_in,
                              void* d_out, int out_size, void* d_ws,
                              size_t ws_size, hipStream_t stream) {
  (void)n_in;
  (void)out_size;
  (void)ws_size;
  const float* z = (const float*)d_in[0];
  const float* cb = (const float*)d_in[1];
  const int N = in_sizes[0] / D;  // 32768
  const int K = in_sizes[1] / D;  // 1024

  // Output layout (flat float32, reference return order):
  float* out_q = (float*)d_out;                     // N*D
  float* out_loss = (float*)d_out + (size_t)N * D;  // 1
  float* out_idx = out_loss + 1;                    // N
  float* out_perp = out_idx + N;                    // 1

  // Workspace: hist[K] (uint), loss_acc[1] (float), pad, cbn[K] (float)
  unsigned int* hist = (unsigned int*)d_ws;
  float* loss_acc = (float*)d_ws + K;
  float* cbn = (float*)d_ws + K + 8;  // 16B-aligned

  vq_norms<<<dim3((K + 255) / 256), dim3(256), 0, stream>>>(cb, cbn, hist,
                                                            loss_acc, K);
  vq_main<<<dim3(N / ROWS), dim3(512), 0, stream>>>(z, cb, cbn, out_q, out_idx,
                                                    hist, loss_acc);
  vq_final<<<dim3(1), dim3(1024), 0, stream>>>(
      hist, loss_acc, out_loss, out_perp, 1.0f / (float)N,
      1.0f / ((float)N * (float)D));
}

// Round 4
// 105.124 us; speedup vs baseline: 3.5248x; 1.2984x over previous
//
#include <hip/hip_runtime.h>
#include <math.h>

// VQ-VAE vector quantizer for MI355X (gfx950).
// z: [32768, 64] fp32, codebook: [1024, 64] fp32.
// Outputs (flat float32, concatenated): quantized_st [32768*64], vq_loss [1],
// indices [32768] (as float), perplexity [1].
//
// R4: MFMA path. Distances via 3-term split-bf16 GEMM:
//   dot(z,e) ~= z_hi.e_hi + z_lo.e_hi + z_hi.e_lo   (drop lo.lo, err ~1e-6)
// computed with mfma_f32_16x16x32_bf16 (A = z rows, B = codes-as-rows, i.e.
// B^T input layout). dist = (rz + en) - 2*dot in fp32 (same final rounding
// grid as the np reference). Rows whose approx top-2 margin < 1e-3 are
// re-checked with the EXACT fp32 arithmetic of the R3 kernel (which passed),
// so indices match R3 unless two true distances agree to ~1e-5.

#define D 64
#define KC 1024

typedef short short8 __attribute__((ext_vector_type(8)));
typedef short short4v __attribute__((ext_vector_type(4)));
typedef float f32x4 __attribute__((ext_vector_type(4)));

__device__ __forceinline__ unsigned short f2bf(float x) {
  unsigned int u = __float_as_uint(x);
  unsigned int r = (u + 0x7fffu + ((u >> 16) & 1u)) >> 16;
  return (unsigned short)r;
}
__device__ __forceinline__ float bf2f(unsigned short h) {
  return __uint_as_float((unsigned int)h << 16);
}

// Precompute: exact fp32 code norms (same arithmetic as R3's vq_norms),
// split-bf16 codebook bsplit[k][128] = [e_hi(64) | e_lo(64)], zero hist/loss.
__global__ __launch_bounds__(256) void vq_prep(
    const float* __restrict__ cb, unsigned short* __restrict__ bsplit,
    float* __restrict__ cbn, unsigned int* __restrict__ hist,
    float* __restrict__ loss_acc) {
  const int k = blockIdx.x * 256 + threadIdx.x;  // 0..1023
  const float4* e = (const float4*)(cb + (size_t)k * D);
  unsigned short* bp = bsplit + (size_t)k * 128;
  float s0 = 0.f, s1 = 0.f, s2 = 0.f, s3 = 0.f;
#pragma unroll
  for (int i = 0; i < 16; ++i) {
    float4 v = e[i];
    s0 = fmaf(v.x, v.x, s0);
    s1 = fmaf(v.y, v.y, s1);
    s2 = fmaf(v.z, v.z, s2);
    s3 = fmaf(v.w, v.w, s3);
    unsigned short h0 = f2bf(v.x), h1 = f2bf(v.y), h2 = f2bf(v.z), h3 = f2bf(v.w);
    short4v hv = {(short)h0, (short)h1, (short)h2, (short)h3};
    short4v lv = {(short)f2bf(v.x - bf2f(h0)), (short)f2bf(v.y - bf2f(h1)),
                  (short)f2bf(v.z - bf2f(h2)), (short)f2bf(v.w - bf2f(h3))};
    *(short4v*)(bp + i * 4) = hv;
    *(short4v*)(bp + 64 + i * 4) = lv;
  }
  cbn[k] = (s0 + s1) + (s2 + s3);
  hist[k] = 0u;
  if (k == 0) loss_acc[0] = 0.f;
}

__global__ __launch_bounds__(256, 2) void vq_main(
    const float* __restrict__ z, const unsigned short* __restrict__ bsplit,
    const float* __restrict__ cbn, const float* __restrict__ cb,
    float* __restrict__ out_q, float* __restrict__ out_idx,
    unsigned int* __restrict__ hist, float* __restrict__ loss_acc) {
  // A' split-bf16 z tile: [64 rows][128 inner], stride 136 (bank-skew; 136/2=68
  // words == 4 mod 32 -> only 2-way aliasing on frag reads, which is free).
  __shared__ unsigned short Ash[64 * 136];
  __shared__ float srzp[1024];
  __shared__ float srz[64];
  __shared__ float candd[4][64][17];  // +1 pad: final scan conflict-free
  __shared__ int candk[4][64][17];
  __shared__ int skf[64];
  __shared__ float swav[4];

  const int tid = threadIdx.x;
  const int lane = tid & 63;
  const int wav = tid >> 6;
  const int quad = lane >> 4;
  const int col = lane & 15;
  const int rowbase = blockIdx.x * 64;

  // ---- prologue: load z tile (coalesced), split to bf16 hi/lo, row norms
  const float4* z4 = (const float4*)(z + (size_t)rowbase * D);
#pragma unroll
  for (int it = 0; it < 4; ++it) {
    int f4 = it * 256 + tid;  // 0..1023 = row*16 + (c4/4)
    int row = f4 >> 4, c4 = (f4 & 15) * 4;
    float4 v = z4[f4];
    srzp[f4] = ((v.x * v.x + v.y * v.y) + (v.z * v.z + v.w * v.w));
    unsigned short h0 = f2bf(v.x), h1 = f2bf(v.y), h2 = f2bf(v.z), h3 = f2bf(v.w);
    short4v hv = {(short)h0, (short)h1, (short)h2, (short)h3};
    short4v lv = {(short)f2bf(v.x - bf2f(h0)), (short)f2bf(v.y - bf2f(h1)),
                  (short)f2bf(v.z - bf2f(h2)), (short)f2bf(v.w - bf2f(h3))};
    *(short4v*)&Ash[row * 136 + c4] = hv;
    *(short4v*)&Ash[row * 136 + 64 + c4] = lv;
  }
  __syncthreads();
  if (tid < 64) {
    float s = 0.f;
#pragma unroll
    for (int i = 0; i < 16; ++i) s += srzp[tid * 16 + i];
    srz[tid] = s;
  }
  __syncthreads();

  // rz per (m-tile, reg): lane holds C rows mt*16 + quad*4 + reg
  float rzv[16];
#pragma unroll
  for (int mt = 0; mt < 4; ++mt)
#pragma unroll
    for (int reg = 0; reg < 4; ++reg)
      rzv[mt * 4 + reg] = srz[mt * 16 + quad * 4 + reg];

  // A fragments in registers: a[mt][{hi0,hi1,lo0,lo1}], 8 bf16 each.
  // A-operand layout: lane holds A[m = col][k = quad*8 + j].
  short8 a[4][4];
#pragma unroll
  for (int mt = 0; mt < 4; ++mt) {
    const unsigned short* base = &Ash[(mt * 16 + col) * 136 + quad * 8];
    a[mt][0] = *(const short8*)(base + 0);    // z_hi k 0..31
    a[mt][1] = *(const short8*)(base + 32);   // z_hi k 32..63
    a[mt][2] = *(const short8*)(base + 64);   // z_lo k 0..31
    a[mt][3] = *(const short8*)(base + 96);   // z_lo k 32..63
  }

  float bestd[16];
  int bestk[16];
#pragma unroll
  for (int i = 0; i < 16; ++i) {
    bestd[i] = 3.4e38f;
    bestk[i] = 0;
  }

  // Each wave scans 256 codes in 16 k-tiles of 16 codes.
  const int k0 = wav * 256;
  for (int kt = 0; kt < 16; ++kt) {
    const int mycode = k0 + kt * 16 + col;
    // B-operand layout: lane holds B[n = col (code)][k = quad*8 + j];
    // codes stored row-major (the B^T pattern). 4 distinct frags.
    const unsigned short* bb = bsplit + (size_t)mycode * 128 + quad * 8;
    short8 b0 = *(const short8*)(bb + 0);    // e_hi k 0..31
    short8 b1 = *(const short8*)(bb + 32);   // e_hi k 32..63
    short8 b2 = *(const short8*)(bb + 64);   // e_lo k 0..31
    short8 b3 = *(const short8*)(bb + 96);   // e_lo k 32..63
    const float en = cbn[mycode];

    f32x4 acc[4];
#pragma unroll
    for (int mt = 0; mt < 4; ++mt) acc[mt] = {0.f, 0.f, 0.f, 0.f};
    // 6 products, 4 independent chains (mt) for MFMA ILP
#pragma unroll
    for (int mt = 0; mt < 4; ++mt)
      acc[mt] = __builtin_amdgcn_mfma_f32_16x16x32_bf16(a[mt][0], b0, acc[mt], 0, 0, 0);
#pragma unroll
    for (int mt = 0; mt < 4; ++mt)
      acc[mt] = __builtin_amdgcn_mfma_f32_16x16x32_bf16(a[mt][1], b1, acc[mt], 0, 0, 0);
#pragma unroll
    for (int mt = 0; mt < 4; ++mt)
      acc[mt] = __builtin_amdgcn_mfma_f32_16x16x32_bf16(a[mt][2], b0, acc[mt], 0, 0, 0);
#pragma unroll
    for (int mt = 0; mt < 4; ++mt)
      acc[mt] = __builtin_amdgcn_mfma_f32_16x16x32_bf16(a[mt][3], b1, acc[mt], 0, 0, 0);
#pragma unroll
    for (int mt = 0; mt < 4; ++mt)
      acc[mt] = __builtin_amdgcn_mfma_f32_16x16x32_bf16(a[mt][0], b2, acc[mt], 0, 0, 0);
#pragma unroll
    for (int mt = 0; mt < 4; ++mt)
      acc[mt] = __builtin_amdgcn_mfma_f32_16x16x32_bf16(a[mt][1], b3, acc[mt], 0, 0, 0);

    // fold into running argmin; C/D layout: col=lane&15, row=quad*4+reg
#pragma unroll
    for (int mt = 0; mt < 4; ++mt)
#pragma unroll
      for (int reg = 0; reg < 4; ++reg) {
        float dist = fmaf(-2.0f, acc[mt][reg], rzv[mt * 4 + reg] + en);
        int i = mt * 4 + reg;
        bool better = dist < bestd[i];  // strict <: ascending k keeps lowest
        bestk[i] = better ? mycode : bestk[i];
        bestd[i] = better ? dist : bestd[i];
      }
  }

  // publish per-lane candidates: per row, 16 col-classes x 4 waves
#pragma unroll
  for (int mt = 0; mt < 4; ++mt)
#pragma unroll
    for (int reg = 0; reg < 4; ++reg) {
      int row = mt * 16 + quad * 4 + reg;
      candd[wav][row][col] = bestd[mt * 4 + reg];
      candk[wav][row][col] = bestk[mt * 4 + reg];
    }
  __syncthreads();

  // ---- final per-row argmin with top-2 + exact fp32 recheck (R3 arithmetic)
  if (tid < 64) {
    float bd1 = 3.4e38f, bd2 = 3.4e38f;
    int bk1 = 0x7fffffff, bk2 = 0x7fffffff;
#pragma unroll
    for (int w = 0; w < 4; ++w)
      for (int c = 0; c < 16; ++c) {
        float dv = candd[w][tid][c];
        int kv = candk[w][tid][c];
        bool b1 = (dv < bd1) || (dv == bd1 && kv < bk1);
        bool b2 = (dv < bd2) || (dv == bd2 && kv < bk2);
        if (b1) {
          bd2 = bd1; bk2 = bk1;
          bd1 = dv; bk1 = kv;
        } else if (b2) {
          bd2 = dv; bk2 = kv;
        }
      }
    if (bd2 - bd1 < 1e-3f) {
      // exact fp32 recompute, bit-identical to the R3 kernel's arithmetic
      const int grow = rowbase + tid;
      const float4* zp = (const float4*)(z + (size_t)grow * D);
      float s0 = 0.f, s1 = 0.f, s2 = 0.f, s3 = 0.f;
#pragma unroll
      for (int i = 0; i < 16; ++i) {
        float4 v = zp[i];
        s0 = fmaf(v.x, v.x, s0);
        s1 = fmaf(v.y, v.y, s1);
        s2 = fmaf(v.z, v.z, s2);
        s3 = fmaf(v.w, v.w, s3);
      }
      const float rzx = (s0 + s1) + (s2 + s3);
      float dx[2];
      int kk[2] = {bk1, bk2};
#pragma unroll
      for (int c = 0; c < 2; ++c) {
        const float4* e4 = (const float4*)(cb + (size_t)kk[c] * D);
        float d0 = 0.f, d1 = 0.f, d2 = 0.f, d3 = 0.f;
#pragma unroll
        for (int i = 0; i < 16; ++i) {
          float4 v = e4[i];
          float4 zv = zp[i];
          d0 = fmaf(zv.x, v.x, d0);
          d1 = fmaf(zv.y, v.y, d1);
          d2 = fmaf(zv.z, v.z, d2);
          d3 = fmaf(zv.w, v.w, d3);
        }
        float dot = (d0 + d1) + (d2 + d3);
        dx[c] = (rzx + cbn[kk[c]]) - 2.0f * dot;
      }
      if ((dx[1] < dx[0]) || (dx[1] == dx[0] && bk2 < bk1)) bk1 = bk2;
    }
    skf[tid] = bk1;
    out_idx[rowbase + tid] = (float)bk1;
    atomicAdd(&hist[bk1], 1u);
  }
  __syncthreads();

  // ---- epilogue: quantized write (exact fp32 codebook rows) + loss partial
  float lsum = 0.f;
#pragma unroll
  for (int it = 0; it < 4; ++it) {
    int f4 = it * 256 + tid;
    int r = f4 >> 4;
    int c4 = (f4 & 15) * 4;
    int bk = skf[r];
    const float4 q = *(const float4*)(cb + (size_t)bk * D + c4);
    const int grow = rowbase + r;
    const float4 zv = *(const float4*)(z + (size_t)grow * D + c4);
    *(float4*)(out_q + (size_t)grow * D + c4) = q;
    float ax = q.x - zv.x, ay = q.y - zv.y, az = q.z - zv.z, aw = q.w - zv.w;
    lsum += ax * ax + ay * ay + az * az + aw * aw;
  }
#pragma unroll
  for (int off = 32; off > 0; off >>= 1) lsum += __shfl_down(lsum, off, 64);
  if (lane == 0) swav[wav] = lsum;
  __syncthreads();
  if (tid == 0) {
    atomicAdd(loss_acc, (swav[0] + swav[1]) + (swav[2] + swav[3]));
  }
}

__global__ __launch_bounds__(1024) void vq_final(
    const unsigned int* __restrict__ hist, const float* __restrict__ loss_acc,
    float* __restrict__ out_loss, float* __restrict__ out_perp, float inv_n,
    float inv_nd) {
  __shared__ float red[1024];
  int t = threadIdx.x;
  float p = (float)hist[t] * inv_n;
  red[t] = p * logf(p + 1e-10f);
  __syncthreads();
  for (int s = 512; s > 0; s >>= 1) {
    if (t < s) red[t] += red[t + s];
    __syncthreads();
  }
  if (t == 0) {
    *out_perp = expf(-red[0]);
    // q_latent + 0.25*e_latent, both numerically mean((q-z)^2)
    *out_loss = 1.25f * loss_acc[0] * inv_nd;
  }
}

extern "C" void kernel_launch(void* const* d_in, const int* in_sizes, int n_in,
                              void* d_out, int out_size, void* d_ws,
                              size_t ws_size, hipStream_t stream) {
  (void)n_in;
  (void)out_size;
  (void)ws_size;
  const float* z = (const float*)d_in[0];
  const float* cb = (const float*)d_in[1];
  const int N = in_sizes[0] / D;  // 32768

  // Output layout (flat float32, reference return order):
  float* out_q = (float*)d_out;                     // N*D
  float* out_loss = (float*)d_out + (size_t)N * D;  // 1
  float* out_idx = out_loss + 1;                    // N
  float* out_perp = out_idx + N;                    // 1

  // Workspace (floats): hist[1024] @0, loss_acc @1024, cbn[1024] @1040,
  // bsplit (short[1024*128]) @ float-idx 2064 (byte 8256, 16B-aligned).
  unsigned int* hist = (unsigned int*)d_ws;
  float* loss_acc = (float*)d_ws + 1024;
  float* cbn = (float*)d_ws + 1040;
  unsigned short* bsplit = (unsigned short*)((float*)d_ws + 2064);

  vq_prep<<<dim3(KC / 256), dim3(256), 0, stream>>>(cb, bsplit, cbn, hist,
                                                    loss_acc);
  vq_main<<<dim3(N / 64), dim3(256), 0, stream>>>(z, bsplit, cbn, cb, out_q,
                                                  out_idx, hist, loss_acc);
  vq_final<<<dim3(1), dim3(1024), 0, stream>>>(
      hist, loss_acc, out_loss, out_perp, 1.0f / (float)N,
      1.0f / ((float)N * (float)D));
}